// Round 6
// baseline (4412.420 us; speedup 1.0000x reference)
//
#include <hip/hip_runtime.h>
#include <cstdint>

#define BB 8
#define CC 256
#define HH 128
#define WW 128
#define HW (HH * WW)

// ---------------------------------------------------------------------------
// Kernel A: per-position channel mean & max of x -> y2 (B, H*W, 2) float2
// interleaved {mean, max}. One block per (b, h) row; 512 threads.
// ---------------------------------------------------------------------------
__global__ __launch_bounds__(512) void reduce_meanmax(const float* __restrict__ x,
                                                      float* __restrict__ y2) {
    const int bh = blockIdx.x;
    const int b  = bh >> 7;
    const int h  = bh & 127;
    const int t  = threadIdx.x;
    const int wq = t & 31;       // float4 column: w = wq*4
    const int cg = t >> 5;       // channel group 0..15 (16 channels each)

    const float* xb = x + ((size_t)(b * CC + cg * 16) * HH + h) * WW;

    float4 s = make_float4(0.f, 0.f, 0.f, 0.f);
    float4 m = make_float4(-INFINITY, -INFINITY, -INFINITY, -INFINITY);
    #pragma unroll 4
    for (int i = 0; i < 16; ++i) {
        float4 v = ((const float4*)(xb + (size_t)i * HW))[wq];
        s.x += v.x; s.y += v.y; s.z += v.z; s.w += v.w;
        m.x = fmaxf(m.x, v.x); m.y = fmaxf(m.y, v.y);
        m.z = fmaxf(m.z, v.z); m.w = fmaxf(m.w, v.w);
    }

    __shared__ float4 ls[16][32];
    __shared__ float4 lm[16][32];
    ls[cg][wq] = s;
    lm[cg][wq] = m;
    __syncthreads();

    if (t < 32) {
        float4 S = ls[0][t];
        float4 M = lm[0][t];
        #pragma unroll
        for (int g = 1; g < 16; ++g) {
            float4 a = ls[g][t];
            float4 c = lm[g][t];
            S.x += a.x; S.y += a.y; S.z += a.z; S.w += a.w;
            M.x = fmaxf(M.x, c.x); M.y = fmaxf(M.y, c.y);
            M.z = fmaxf(M.z, c.z); M.w = fmaxf(M.w, c.w);
        }
        const float inv = 1.0f / 256.0f;
        float4 o0 = make_float4(S.x * inv, M.x, S.y * inv, M.y);
        float4 o1 = make_float4(S.z * inv, M.z, S.w * inv, M.w);
        float4* yo = (float4*)(y2 + ((size_t)b * HW + (size_t)h * WW) * 2);
        yo[2 * t]     = o0;
        yo[2 * t + 1] = o1;
    }
}

// round-to-nearest-even f32 -> bf16 (low 16 bits)
__device__ __forceinline__ uint32_t f2bf(float f) {
    uint32_t u = __float_as_uint(f);
    return (u + 0x7FFFu + ((u >> 16) & 1u)) >> 16;
}

// ---------------------------------------------------------------------------
// Kernel B: wave-independent conv + sampling. Block = 256 threads (4 waves);
// wave wv owns positions [32*wv, 32*wv+32) of the row, in chunks of 8.
// Lane l < 49 = tap. Each wave computes ALL THREE channel types (dy/dx/mask)
// for its positions -> conv output is already tap-per-lane for sampling:
// no cross-wave exchange, no main-loop barriers.
// Weights: LDS, bf16x2-packed [type][tap][rc]; lane stride 49 u32 -> 2-way
// (free) conflicts only.
// ---------------------------------------------------------------------------
__global__ __launch_bounds__(256, 4) void deform_att(
    const float* __restrict__ y2,
    const float* __restrict__ w_off, const float* __restrict__ b_off,
    const float* __restrict__ w_dcn, const float* __restrict__ b_dcn,
    const float* __restrict__ bn_gamma, const float* __restrict__ bn_beta,
    const float* __restrict__ bn_mean, const float* __restrict__ bn_var,
    float* __restrict__ out)
{
    const int bh = blockIdx.x;
    const int b  = bh >> 7;
    const int h  = bh & 127;
    const int t  = threadIdx.x;
    const int wv = t >> 6;          // wave: position range owner
    const int l  = t & 63;
    const bool act = (l < 49);
    const int ls = act ? l : 0;     // clamped tap index

    __shared__ uint32_t wlds[3][49][49];  // [type][tap][rc] packed bf16 {plane0-w, plane1-w}
    __shared__ float patch[2][7][136];    // zero-padded row window
    __shared__ float gate_row[128];

    const float2* y2b = (const float2*)y2 + (size_t)b * HW;

    // ---- stage packed weights into LDS (147 channels x 49 taps) ----
    for (int idx = t; idx < 147 * 49; idx += 256) {
        const int ch = idx / 49;         // source channel 0..146
        const int k  = idx % 49;
        const int ty  = (ch < 98) ? (ch & 1) : 2;
        const int tap = (ch < 98) ? (ch >> 1) : (ch - 98);
        const float* wp = w_off + (size_t)ch * 98;
        wlds[ty][tap][k] = f2bf(wp[k]) | (f2bf(wp[49 + k]) << 16);
    }

    // ---- stage the zero-padded 2x7x134 patch window into LDS ----
    for (int i = t; i < 7 * 136; i += 256) {
        const int r  = i / 136;
        const int xi = i % 136;
        const int xx = xi - 3;
        const int yy = h + r - 3;
        float2 v = make_float2(0.f, 0.f);
        if (yy >= 0 && yy < HH && xx >= 0 && xx < WW)
            v = y2b[yy * WW + xx];
        patch[0][r][xi] = v.x;
        patch[1][r][xi] = v.y;
    }

    // per-lane (tap) constants
    const float b_dy = b_off[2 * ls];
    const float b_dx = b_off[2 * ls + 1];
    const float b_m  = b_off[98 + ls];
    const float wd0 = w_dcn[ls];
    const float wd1 = w_dcn[49 + ls];
    const int kr = ls / 7;
    const int kc = ls % 7;
    const float bscale = bn_gamma[0] * rsqrtf(bn_var[0] + 1e-5f);
    const float gB = (b_dcn[0] - bn_mean[0]) * bscale + bn_beta[0];

    __syncthreads();

    // ---- 4 chunks of 8 positions, fully wave-local ----
    #pragma unroll 1
    for (int sub = 0; sub < 4; ++sub) {
        const int base = wv * 32 + sub * 8;

        float acc0[8], acc1[8], acc2[8];
        #pragma unroll
        for (int pp = 0; pp < 8; ++pp) { acc0[pp] = b_dy; acc1[pp] = b_dx; acc2[pp] = b_m; }

        #pragma unroll
        for (int r = 0; r < 7; ++r) {
            float v0[14], v1[14];
            #pragma unroll
            for (int q = 0; q < 7; ++q) {
                float2 a  = *(const float2*)&patch[0][r][base + 2 * q];
                float2 bb = *(const float2*)&patch[1][r][base + 2 * q];
                v0[2 * q] = a.x;  v0[2 * q + 1] = a.y;
                v1[2 * q] = bb.x; v1[2 * q + 1] = bb.y;
            }
            #pragma unroll
            for (int c = 0; c < 7; ++c) {
                const int rc = r * 7 + c;
                const uint32_t pkY = wlds[0][ls][rc];
                const uint32_t pkX = wlds[1][ls][rc];
                const uint32_t pkM = wlds[2][ls][rc];
                const float wY0 = __uint_as_float(pkY << 16);
                const float wY1 = __uint_as_float(pkY & 0xFFFF0000u);
                const float wX0 = __uint_as_float(pkX << 16);
                const float wX1 = __uint_as_float(pkX & 0xFFFF0000u);
                const float wM0 = __uint_as_float(pkM << 16);
                const float wM1 = __uint_as_float(pkM & 0xFFFF0000u);
                #pragma unroll
                for (int pp = 0; pp < 8; ++pp) {
                    const float a = v0[pp + c];
                    const float bb = v1[pp + c];
                    acc0[pp] = fmaf(wY0, a, acc0[pp]);
                    acc0[pp] = fmaf(wY1, bb, acc0[pp]);
                    acc1[pp] = fmaf(wX0, a, acc1[pp]);
                    acc1[pp] = fmaf(wX1, bb, acc1[pp]);
                    acc2[pp] = fmaf(wM0, a, acc2[pp]);
                    acc2[pp] = fmaf(wM1, bb, acc2[pp]);
                }
            }
        }

        // ---- sampling: 8 positions, all operands in-lane (tap = lane) ----
        #pragma unroll
        for (int pp = 0; pp < 8; ++pp) {
            const int pos = base + pp;

            const float mk = 1.0f / (1.0f + __expf(-acc2[pp]));

            const float fy = (float)(h + kr - 3) + acc0[pp];
            const float fx = (float)(pos + kc - 3) + acc1[pp];
            const float fly = floorf(fy), flx = floorf(fx);
            const int iy0 = (int)fly, ix0 = (int)flx;
            const int iy1 = iy0 + 1,  ix1 = ix0 + 1;
            const float wy1 = fy - fly, wy0 = 1.0f - wy1;
            const float wx1 = fx - flx, wx0 = 1.0f - wx1;

            const float vy0 = (iy0 >= 0 && iy0 < HH) ? 1.0f : 0.0f;
            const float vy1 = (iy1 >= 0 && iy1 < HH) ? 1.0f : 0.0f;
            const float vx0 = (ix0 >= 0 && ix0 < WW) ? 1.0f : 0.0f;
            const float vx1 = (ix1 >= 0 && ix1 < WW) ? 1.0f : 0.0f;

            const int cy0 = min(max(iy0, 0), HH - 1) * WW;
            const int cy1 = min(max(iy1, 0), HH - 1) * WW;
            const int cx0 = min(max(ix0, 0), WW - 1);
            const int cx1 = min(max(ix1, 0), WW - 1);

            const float w00 = wy0 * wx0 * vy0 * vx0;
            const float w01 = wy0 * wx1 * vy0 * vx1;
            const float w10 = wy1 * wx0 * vy1 * vx0;
            const float w11 = wy1 * wx1 * vy1 * vx1;

            const float2 g00 = y2b[cy0 + cx0];
            const float2 g01 = y2b[cy0 + cx1];
            const float2 g10 = y2b[cy1 + cx0];
            const float2 g11 = y2b[cy1 + cx1];

            const float v0s = g00.x * w00 + g01.x * w01 + g10.x * w10 + g11.x * w11;
            const float v1s = g00.y * w00 + g01.y * w01 + g10.y * w10 + g11.y * w11;

            float tval = mk * fmaf(v0s, wd0, v1s * wd1);
            tval = act ? tval : 0.0f;

            float ssum = tval;
            #pragma unroll
            for (int off = 1; off < 64; off <<= 1)
                ssum += __shfl_xor(ssum, off);

            if (l == 0) {
                const float o = ssum * bscale + gB;
                gate_row[pos] = 1.0f / (1.0f + __expf(-o));
            }
        }
    }

    __syncthreads();

    // ---- broadcast write: gate_row -> all 256 channels ----
    const size_t ob = (size_t)b * CC * HW + (size_t)h * WW;
    const float4* gr = (const float4*)gate_row;
    for (int idx = t; idx < CC * 32; idx += 256) {
        const int c  = idx >> 5;
        const int wq = idx & 31;
        ((float4*)(out + ob + (size_t)c * HW))[wq] = gr[wq];
    }
}

extern "C" void kernel_launch(void* const* d_in, const int* in_sizes, int n_in,
                              void* d_out, int out_size, void* d_ws, size_t ws_size,
                              hipStream_t stream) {
    const float* x        = (const float*)d_in[0];
    const float* w_off    = (const float*)d_in[1];
    const float* b_off    = (const float*)d_in[2];
    const float* w_dcn    = (const float*)d_in[3];
    const float* b_dcn    = (const float*)d_in[4];
    const float* bn_gamma = (const float*)d_in[5];
    const float* bn_beta  = (const float*)d_in[6];
    const float* bn_mean  = (const float*)d_in[7];
    const float* bn_var   = (const float*)d_in[8];
    float* out = (float*)d_out;

    float* y2 = (float*)d_ws;   // (B, H*W, 2) interleaved mean/max = 1 MiB

    reduce_meanmax<<<BB * HH, 512, 0, stream>>>(x, y2);
    deform_att<<<BB * HH, 256, 0, stream>>>(y2, w_off, b_off, w_dcn, b_dcn,
                                            bn_gamma, bn_beta, bn_mean, bn_var,
                                            out);
}

// Round 7
// 247.818 us; speedup vs baseline: 17.8051x; 17.8051x over previous
//
#include <hip/hip_runtime.h>
#include <cstdint>

#define BB 8
#define CC 256
#define HH 128
#define WW 128
#define HW (HH * WW)

// ---------------------------------------------------------------------------
// Kernel A: per-position channel mean & max of x -> y2 (B, H*W, 2) float2
// interleaved {mean, max}. One block per (b, h) row; 512 threads.
// ---------------------------------------------------------------------------
__global__ __launch_bounds__(512) void reduce_meanmax(const float* __restrict__ x,
                                                      float* __restrict__ y2) {
    const int bh = blockIdx.x;
    const int b  = bh >> 7;
    const int h  = bh & 127;
    const int t  = threadIdx.x;
    const int wq = t & 31;       // float4 column: w = wq*4
    const int cg = t >> 5;       // channel group 0..15 (16 channels each)

    const float* xb = x + ((size_t)(b * CC + cg * 16) * HH + h) * WW;

    float4 s = make_float4(0.f, 0.f, 0.f, 0.f);
    float4 m = make_float4(-INFINITY, -INFINITY, -INFINITY, -INFINITY);
    #pragma unroll 4
    for (int i = 0; i < 16; ++i) {
        float4 v = ((const float4*)(xb + (size_t)i * HW))[wq];
        s.x += v.x; s.y += v.y; s.z += v.z; s.w += v.w;
        m.x = fmaxf(m.x, v.x); m.y = fmaxf(m.y, v.y);
        m.z = fmaxf(m.z, v.z); m.w = fmaxf(m.w, v.w);
    }

    __shared__ float4 ls[16][32];
    __shared__ float4 lm[16][32];
    ls[cg][wq] = s;
    lm[cg][wq] = m;
    __syncthreads();

    if (t < 32) {
        float4 S = ls[0][t];
        float4 M = lm[0][t];
        #pragma unroll
        for (int g = 1; g < 16; ++g) {
            float4 a = ls[g][t];
            float4 c = lm[g][t];
            S.x += a.x; S.y += a.y; S.z += a.z; S.w += a.w;
            M.x = fmaxf(M.x, c.x); M.y = fmaxf(M.y, c.y);
            M.z = fmaxf(M.z, c.z); M.w = fmaxf(M.w, c.w);
        }
        const float inv = 1.0f / 256.0f;
        float4 o0 = make_float4(S.x * inv, M.x, S.y * inv, M.y);
        float4 o1 = make_float4(S.z * inv, M.z, S.w * inv, M.w);
        float4* yo = (float4*)(y2 + ((size_t)b * HW + (size_t)h * WW) * 2);
        yo[2 * t]     = o0;
        yo[2 * t + 1] = o1;
    }
}

// round-to-nearest-even f32 -> bf16 (low 16 bits)
__device__ __forceinline__ uint32_t f2bf(float f) {
    uint32_t u = __float_as_uint(f);
    return (u + 0x7FFFu + ((u >> 16) & 1u)) >> 16;
}

// ---------------------------------------------------------------------------
// Kernel B: wave-independent conv + sampling. Block = 256 threads (4 waves);
// wave wv owns positions [32*wv, 32*wv+32) of the row, in chunks of 8.
// Lane l < 49 = tap. Each wave computes ALL THREE channel types (dy/dx/mask)
// for its positions -> conv output is already tap-per-lane for sampling:
// no cross-wave exchange, no main-loop barriers.
// Weights: LDS, bf16x2-packed [type][tap][rc]; lane stride 49 u32 -> 2-way
// (free) conflicts only.
// NOTE: no min-waves occupancy hint — every run with one (r3/r4/r6) made the
// allocator pick a too-tight VGPR cap and spill to scratch (up to 5.9 GB).
// ---------------------------------------------------------------------------
__global__ __launch_bounds__(256) void deform_att(
    const float* __restrict__ y2,
    const float* __restrict__ w_off, const float* __restrict__ b_off,
    const float* __restrict__ w_dcn, const float* __restrict__ b_dcn,
    const float* __restrict__ bn_gamma, const float* __restrict__ bn_beta,
    const float* __restrict__ bn_mean, const float* __restrict__ bn_var,
    float* __restrict__ out)
{
    const int bh = blockIdx.x;
    const int b  = bh >> 7;
    const int h  = bh & 127;
    const int t  = threadIdx.x;
    const int wv = t >> 6;          // wave: position range owner
    const int l  = t & 63;
    const bool act = (l < 49);
    const int ls = act ? l : 0;     // clamped tap index

    __shared__ uint32_t wlds[3][49][49];  // [type][tap][rc] packed bf16 {plane0-w, plane1-w}
    __shared__ float patch[2][7][136];    // zero-padded row window
    __shared__ float gate_row[128];

    const float2* y2b = (const float2*)y2 + (size_t)b * HW;

    // ---- stage packed weights into LDS (147 channels x 49 taps) ----
    for (int idx = t; idx < 147 * 49; idx += 256) {
        const int ch = idx / 49;         // source channel 0..146
        const int k  = idx % 49;
        const int ty  = (ch < 98) ? (ch & 1) : 2;
        const int tap = (ch < 98) ? (ch >> 1) : (ch - 98);
        const float* wp = w_off + (size_t)ch * 98;
        wlds[ty][tap][k] = f2bf(wp[k]) | (f2bf(wp[49 + k]) << 16);
    }

    // ---- stage the zero-padded 2x7x134 patch window into LDS ----
    for (int i = t; i < 7 * 136; i += 256) {
        const int r  = i / 136;
        const int xi = i % 136;
        const int xx = xi - 3;
        const int yy = h + r - 3;
        float2 v = make_float2(0.f, 0.f);
        if (yy >= 0 && yy < HH && xx >= 0 && xx < WW)
            v = y2b[yy * WW + xx];
        patch[0][r][xi] = v.x;
        patch[1][r][xi] = v.y;
    }

    // per-lane (tap) constants
    const float b_dy = b_off[2 * ls];
    const float b_dx = b_off[2 * ls + 1];
    const float b_m  = b_off[98 + ls];
    const float wd0 = w_dcn[ls];
    const float wd1 = w_dcn[49 + ls];
    const int kr = ls / 7;
    const int kc = ls % 7;
    const float bscale = bn_gamma[0] * rsqrtf(bn_var[0] + 1e-5f);
    const float gB = (b_dcn[0] - bn_mean[0]) * bscale + bn_beta[0];

    __syncthreads();

    // ---- 4 chunks of 8 positions, fully wave-local ----
    #pragma unroll 1
    for (int sub = 0; sub < 4; ++sub) {
        const int base = wv * 32 + sub * 8;

        float acc0[8], acc1[8], acc2[8];
        #pragma unroll
        for (int pp = 0; pp < 8; ++pp) { acc0[pp] = b_dy; acc1[pp] = b_dx; acc2[pp] = b_m; }

        #pragma unroll
        for (int r = 0; r < 7; ++r) {
            float v0[14], v1[14];
            #pragma unroll
            for (int q = 0; q < 7; ++q) {
                float2 a  = *(const float2*)&patch[0][r][base + 2 * q];
                float2 bb = *(const float2*)&patch[1][r][base + 2 * q];
                v0[2 * q] = a.x;  v0[2 * q + 1] = a.y;
                v1[2 * q] = bb.x; v1[2 * q + 1] = bb.y;
            }
            #pragma unroll
            for (int c = 0; c < 7; ++c) {
                const int rc = r * 7 + c;
                const uint32_t pkY = wlds[0][ls][rc];
                const uint32_t pkX = wlds[1][ls][rc];
                const uint32_t pkM = wlds[2][ls][rc];
                const float wY0 = __uint_as_float(pkY << 16);
                const float wY1 = __uint_as_float(pkY & 0xFFFF0000u);
                const float wX0 = __uint_as_float(pkX << 16);
                const float wX1 = __uint_as_float(pkX & 0xFFFF0000u);
                const float wM0 = __uint_as_float(pkM << 16);
                const float wM1 = __uint_as_float(pkM & 0xFFFF0000u);
                #pragma unroll
                for (int pp = 0; pp < 8; ++pp) {
                    const float a = v0[pp + c];
                    const float bb = v1[pp + c];
                    acc0[pp] = fmaf(wY0, a, acc0[pp]);
                    acc0[pp] = fmaf(wY1, bb, acc0[pp]);
                    acc1[pp] = fmaf(wX0, a, acc1[pp]);
                    acc1[pp] = fmaf(wX1, bb, acc1[pp]);
                    acc2[pp] = fmaf(wM0, a, acc2[pp]);
                    acc2[pp] = fmaf(wM1, bb, acc2[pp]);
                }
            }
        }

        // ---- sampling: 8 positions, all operands in-lane (tap = lane) ----
        #pragma unroll
        for (int pp = 0; pp < 8; ++pp) {
            const int pos = base + pp;

            const float mk = 1.0f / (1.0f + __expf(-acc2[pp]));

            const float fy = (float)(h + kr - 3) + acc0[pp];
            const float fx = (float)(pos + kc - 3) + acc1[pp];
            const float fly = floorf(fy), flx = floorf(fx);
            const int iy0 = (int)fly, ix0 = (int)flx;
            const int iy1 = iy0 + 1,  ix1 = ix0 + 1;
            const float wy1 = fy - fly, wy0 = 1.0f - wy1;
            const float wx1 = fx - flx, wx0 = 1.0f - wx1;

            const float vy0 = (iy0 >= 0 && iy0 < HH) ? 1.0f : 0.0f;
            const float vy1 = (iy1 >= 0 && iy1 < HH) ? 1.0f : 0.0f;
            const float vx0 = (ix0 >= 0 && ix0 < WW) ? 1.0f : 0.0f;
            const float vx1 = (ix1 >= 0 && ix1 < WW) ? 1.0f : 0.0f;

            const int cy0 = min(max(iy0, 0), HH - 1) * WW;
            const int cy1 = min(max(iy1, 0), HH - 1) * WW;
            const int cx0 = min(max(ix0, 0), WW - 1);
            const int cx1 = min(max(ix1, 0), WW - 1);

            const float w00 = wy0 * wx0 * vy0 * vx0;
            const float w01 = wy0 * wx1 * vy0 * vx1;
            const float w10 = wy1 * wx0 * vy1 * vx0;
            const float w11 = wy1 * wx1 * vy1 * vx1;

            const float2 g00 = y2b[cy0 + cx0];
            const float2 g01 = y2b[cy0 + cx1];
            const float2 g10 = y2b[cy1 + cx0];
            const float2 g11 = y2b[cy1 + cx1];

            const float v0s = g00.x * w00 + g01.x * w01 + g10.x * w10 + g11.x * w11;
            const float v1s = g00.y * w00 + g01.y * w01 + g10.y * w10 + g11.y * w11;

            float tval = mk * fmaf(v0s, wd0, v1s * wd1);
            tval = act ? tval : 0.0f;

            float ssum = tval;
            #pragma unroll
            for (int off = 1; off < 64; off <<= 1)
                ssum += __shfl_xor(ssum, off);

            if (l == 0) {
                const float o = ssum * bscale + gB;
                gate_row[pos] = 1.0f / (1.0f + __expf(-o));
            }
        }
    }

    __syncthreads();

    // ---- broadcast write: gate_row -> all 256 channels ----
    const size_t ob = (size_t)b * CC * HW + (size_t)h * WW;
    const float4* gr = (const float4*)gate_row;
    for (int idx = t; idx < CC * 32; idx += 256) {
        const int c  = idx >> 5;
        const int wq = idx & 31;
        ((float4*)(out + ob + (size_t)c * HW))[wq] = gr[wq];
    }
}

extern "C" void kernel_launch(void* const* d_in, const int* in_sizes, int n_in,
                              void* d_out, int out_size, void* d_ws, size_t ws_size,
                              hipStream_t stream) {
    const float* x        = (const float*)d_in[0];
    const float* w_off    = (const float*)d_in[1];
    const float* b_off    = (const float*)d_in[2];
    const float* w_dcn    = (const float*)d_in[3];
    const float* b_dcn    = (const float*)d_in[4];
    const float* bn_gamma = (const float*)d_in[5];
    const float* bn_beta  = (const float*)d_in[6];
    const float* bn_mean  = (const float*)d_in[7];
    const float* bn_var   = (const float*)d_in[8];
    float* out = (float*)d_out;

    float* y2 = (float*)d_ws;   // (B, H*W, 2) interleaved mean/max = 1 MiB

    reduce_meanmax<<<BB * HH, 512, 0, stream>>>(x, y2);
    deform_att<<<BB * HH, 256, 0, stream>>>(y2, w_off, b_off, w_dcn, b_dcn,
                                            bn_gamma, bn_beta, bn_mean, bn_var,
                                            out);
}

// Round 8
// 106.414 us; speedup vs baseline: 41.4646x; 2.3288x over previous
//
#include <hip/hip_runtime.h>
#include <cstdint>

#define BB 8
#define CC 256
#define HH 128
#define WW 128
#define HW (HH * WW)

// ---------------------------------------------------------------------------
// Kernel A: per-position channel mean & max of x -> y2 (B, H*W, 2) float2
// interleaved {mean, max}. One block per (b, h) row; 512 threads.
// ---------------------------------------------------------------------------
__global__ __launch_bounds__(512) void reduce_meanmax(const float* __restrict__ x,
                                                      float* __restrict__ y2) {
    const int bh = blockIdx.x;
    const int b  = bh >> 7;
    const int h  = bh & 127;
    const int t  = threadIdx.x;
    const int wq = t & 31;       // float4 column: w = wq*4
    const int cg = t >> 5;       // channel group 0..15 (16 channels each)

    const float* xb = x + ((size_t)(b * CC + cg * 16) * HH + h) * WW;

    float4 s = make_float4(0.f, 0.f, 0.f, 0.f);
    float4 m = make_float4(-INFINITY, -INFINITY, -INFINITY, -INFINITY);
    #pragma unroll 4
    for (int i = 0; i < 16; ++i) {
        float4 v = ((const float4*)(xb + (size_t)i * HW))[wq];
        s.x += v.x; s.y += v.y; s.z += v.z; s.w += v.w;
        m.x = fmaxf(m.x, v.x); m.y = fmaxf(m.y, v.y);
        m.z = fmaxf(m.z, v.z); m.w = fmaxf(m.w, v.w);
    }

    __shared__ float4 ls[16][32];
    __shared__ float4 lm[16][32];
    ls[cg][wq] = s;
    lm[cg][wq] = m;
    __syncthreads();

    if (t < 32) {
        float4 S = ls[0][t];
        float4 M = lm[0][t];
        #pragma unroll
        for (int g = 1; g < 16; ++g) {
            float4 a = ls[g][t];
            float4 c = lm[g][t];
            S.x += a.x; S.y += a.y; S.z += a.z; S.w += a.w;
            M.x = fmaxf(M.x, c.x); M.y = fmaxf(M.y, c.y);
            M.z = fmaxf(M.z, c.z); M.w = fmaxf(M.w, c.w);
        }
        const float inv = 1.0f / 256.0f;
        float4 o0 = make_float4(S.x * inv, M.x, S.y * inv, M.y);
        float4 o1 = make_float4(S.z * inv, M.z, S.w * inv, M.w);
        float4* yo = (float4*)(y2 + ((size_t)b * HW + (size_t)h * WW) * 2);
        yo[2 * t]     = o0;
        yo[2 * t + 1] = o1;
    }
}

// round-to-nearest-even f32 -> bf16 (low 16 bits)
__device__ __forceinline__ uint32_t f2bf(float f) {
    uint32_t u = __float_as_uint(f);
    return (u + 0x7FFFu + ((u >> 16) & 1u)) >> 16;
}

// ---------------------------------------------------------------------------
// Kernel B: wave-independent conv + sampling. Block = 256 threads (4 waves);
// wave wv owns positions [32*wv, 32*wv+32), in chunks of 8. Lane = tap.
// Conv inner op: v_dot2_f32_bf16 on bf16x2-packed {mean,max} patch values
// against bf16x2-packed {plane0,plane1} weights -> one instr per tap/pos.
// Weights stay in LDS; an asm-opaque tap index per chunk prevents LICM from
// hoisting 147 weight reads into registers (r7: VGPR 256 -> 2 waves/SIMD).
// No min-waves hint (r3/r4/r6: any hint -> tight VGPR cap -> GB-scale spill).
// ---------------------------------------------------------------------------
__global__ __launch_bounds__(256) void deform_att(
    const float* __restrict__ y2,
    const float* __restrict__ w_off, const float* __restrict__ b_off,
    const float* __restrict__ w_dcn, const float* __restrict__ b_dcn,
    const float* __restrict__ bn_gamma, const float* __restrict__ bn_beta,
    const float* __restrict__ bn_mean, const float* __restrict__ bn_var,
    float* __restrict__ out)
{
    const int bh = blockIdx.x;
    const int b  = bh >> 7;
    const int h  = bh & 127;
    const int t  = threadIdx.x;
    const int wv = t >> 6;          // wave: position range owner
    const int l  = t & 63;
    const bool act = (l < 49);
    const int ls = act ? l : 0;     // clamped tap index

    __shared__ uint32_t wlds[3][49][49];   // [type][tap][rc] bf16x2 {plane0-w, plane1-w}
    __shared__ uint32_t patch_pk[7][136];  // bf16x2 {mean, max}, zero-padded row window
    __shared__ float gate_row[128];

    const float2* y2b = (const float2*)y2 + (size_t)b * HW;

    // ---- stage packed weights into LDS (147 channels x 49 taps) ----
    for (int idx = t; idx < 147 * 49; idx += 256) {
        const int ch = idx / 49;         // source channel 0..146
        const int k  = idx % 49;
        const int ty  = (ch < 98) ? (ch & 1) : 2;
        const int tap = (ch < 98) ? (ch >> 1) : (ch - 98);
        const float* wp = w_off + (size_t)ch * 98;
        wlds[ty][tap][k] = f2bf(wp[k]) | (f2bf(wp[49 + k]) << 16);
    }

    // ---- stage the zero-padded bf16x2 patch window into LDS ----
    for (int i = t; i < 7 * 136; i += 256) {
        const int r  = i / 136;
        const int xi = i % 136;
        const int xx = xi - 3;
        const int yy = h + r - 3;
        uint32_t v = 0;
        if (yy >= 0 && yy < HH && xx >= 0 && xx < WW) {
            float2 g = y2b[yy * WW + xx];
            v = f2bf(g.x) | (f2bf(g.y) << 16);
        }
        patch_pk[r][xi] = v;
    }

    // per-lane (tap) constants
    const float b_dy = b_off[2 * ls];
    const float b_dx = b_off[2 * ls + 1];
    const float b_m  = b_off[98 + ls];
    const float wd0 = w_dcn[ls];
    const float wd1 = w_dcn[49 + ls];
    const int kr = ls / 7;
    const int kc = ls % 7;
    const float bscale = bn_gamma[0] * rsqrtf(bn_var[0] + 1e-5f);
    const float gB = (b_dcn[0] - bn_mean[0]) * bscale + bn_beta[0];

    __syncthreads();

    // ---- 4 chunks of 8 positions, fully wave-local ----
    #pragma unroll 1
    for (int sub = 0; sub < 4; ++sub) {
        const int base = wv * 32 + sub * 8;

        // opaque tap index: defeats cross-chunk CSE/LICM of the weight reads
        unsigned wls = (unsigned)ls;
        asm volatile("" : "+v"(wls));

        float acc0[8], acc1[8], acc2[8];
        #pragma unroll
        for (int pp = 0; pp < 8; ++pp) { acc0[pp] = b_dy; acc1[pp] = b_dx; acc2[pp] = b_m; }

        #pragma unroll
        for (int r = 0; r < 7; ++r) {
            uint32_t vpk[14];                        // wave-uniform -> LDS broadcast reads
            #pragma unroll
            for (int q = 0; q < 14; ++q) vpk[q] = patch_pk[r][base + q];

            #pragma unroll
            for (int c = 0; c < 7; ++c) {
                const int rc = r * 7 + c;
                const uint32_t wY = wlds[0][wls][rc];   // lane stride 49 u32: 2-way = free
                const uint32_t wX = wlds[1][wls][rc];
                const uint32_t wM = wlds[2][wls][rc];
                #pragma unroll
                for (int pp = 0; pp < 8; ++pp) {
                    asm("v_dot2_f32_bf16 %0, %1, %2, %0"
                        : "+v"(acc0[pp]) : "v"(wY), "v"(vpk[pp + c]));
                    asm("v_dot2_f32_bf16 %0, %1, %2, %0"
                        : "+v"(acc1[pp]) : "v"(wX), "v"(vpk[pp + c]));
                    asm("v_dot2_f32_bf16 %0, %1, %2, %0"
                        : "+v"(acc2[pp]) : "v"(wM), "v"(vpk[pp + c]));
                }
            }
        }

        // ---- sampling: 8 positions, all operands in-lane (tap = lane) ----
        #pragma unroll
        for (int pp = 0; pp < 8; ++pp) {
            const int pos = base + pp;

            const float mk = 1.0f / (1.0f + __expf(-acc2[pp]));

            const float fy = (float)(h + kr - 3) + acc0[pp];
            const float fx = (float)(pos + kc - 3) + acc1[pp];
            const float fly = floorf(fy), flx = floorf(fx);
            const int iy0 = (int)fly, ix0 = (int)flx;
            const int iy1 = iy0 + 1,  ix1 = ix0 + 1;
            const float wy1 = fy - fly, wy0 = 1.0f - wy1;
            const float wx1 = fx - flx, wx0 = 1.0f - wx1;

            const float vy0 = (iy0 >= 0 && iy0 < HH) ? 1.0f : 0.0f;
            const float vy1 = (iy1 >= 0 && iy1 < HH) ? 1.0f : 0.0f;
            const float vx0 = (ix0 >= 0 && ix0 < WW) ? 1.0f : 0.0f;
            const float vx1 = (ix1 >= 0 && ix1 < WW) ? 1.0f : 0.0f;

            const int cy0 = min(max(iy0, 0), HH - 1) * WW;
            const int cy1 = min(max(iy1, 0), HH - 1) * WW;
            const int cx0 = min(max(ix0, 0), WW - 1);
            const int cx1 = min(max(ix1, 0), WW - 1);

            const float w00 = wy0 * wx0 * vy0 * vx0;
            const float w01 = wy0 * wx1 * vy0 * vx1;
            const float w10 = wy1 * wx0 * vy1 * vx0;
            const float w11 = wy1 * wx1 * vy1 * vx1;

            const float2 g00 = y2b[cy0 + cx0];
            const float2 g01 = y2b[cy0 + cx1];
            const float2 g10 = y2b[cy1 + cx0];
            const float2 g11 = y2b[cy1 + cx1];

            const float v0s = g00.x * w00 + g01.x * w01 + g10.x * w10 + g11.x * w11;
            const float v1s = g00.y * w00 + g01.y * w01 + g10.y * w10 + g11.y * w11;

            float tval = mk * fmaf(v0s, wd0, v1s * wd1);
            tval = act ? tval : 0.0f;

            float ssum = tval;
            #pragma unroll
            for (int off = 1; off < 64; off <<= 1)
                ssum += __shfl_xor(ssum, off);

            if (l == 0) {
                const float o = ssum * bscale + gB;
                gate_row[pos] = 1.0f / (1.0f + __expf(-o));
            }
        }
    }

    __syncthreads();

    // ---- broadcast write: gate_row -> all 256 channels ----
    const size_t ob = (size_t)b * CC * HW + (size_t)h * WW;
    const float4* gr = (const float4*)gate_row;
    for (int idx = t; idx < CC * 32; idx += 256) {
        const int c  = idx >> 5;
        const int wq = idx & 31;
        ((float4*)(out + ob + (size_t)c * HW))[wq] = gr[wq];
    }
}

extern "C" void kernel_launch(void* const* d_in, const int* in_sizes, int n_in,
                              void* d_out, int out_size, void* d_ws, size_t ws_size,
                              hipStream_t stream) {
    const float* x        = (const float*)d_in[0];
    const float* w_off    = (const float*)d_in[1];
    const float* b_off    = (const float*)d_in[2];
    const float* w_dcn    = (const float*)d_in[3];
    const float* b_dcn    = (const float*)d_in[4];
    const float* bn_gamma = (const float*)d_in[5];
    const float* bn_beta  = (const float*)d_in[6];
    const float* bn_mean  = (const float*)d_in[7];
    const float* bn_var   = (const float*)d_in[8];
    float* out = (float*)d_out;

    float* y2 = (float*)d_ws;   // (B, H*W, 2) interleaved mean/max = 1 MiB

    reduce_meanmax<<<BB * HH, 512, 0, stream>>>(x, y2);
    deform_att<<<BB * HH, 256, 0, stream>>>(y2, w_off, b_off, w_dcn, b_dcn,
                                            bn_gamma, bn_beta, bn_mean, bn_var,
                                            out);
}

// Round 9
// 97.780 us; speedup vs baseline: 45.1259x; 1.0883x over previous
//
#include <hip/hip_runtime.h>
#include <cstdint>

#define BB 8
#define CC 256
#define HH 128
#define WW 128
#define HW (HH * WW)

typedef __attribute__((ext_vector_type(8))) short bf16x8;
typedef __attribute__((ext_vector_type(4))) float f32x4;

// ---------------------------------------------------------------------------
// Kernel A: per-position channel mean & max of x -> y2 (B, H*W, 2) float2
// interleaved {mean, max}. One block per (b, h) row; 512 threads.
// ---------------------------------------------------------------------------
__global__ __launch_bounds__(512) void reduce_meanmax(const float* __restrict__ x,
                                                      float* __restrict__ y2) {
    const int bh = blockIdx.x;
    const int b  = bh >> 7;
    const int h  = bh & 127;
    const int t  = threadIdx.x;
    const int wq = t & 31;       // float4 column: w = wq*4
    const int cg = t >> 5;       // channel group 0..15 (16 channels each)

    const float* xb = x + ((size_t)(b * CC + cg * 16) * HH + h) * WW;

    float4 s = make_float4(0.f, 0.f, 0.f, 0.f);
    float4 m = make_float4(-INFINITY, -INFINITY, -INFINITY, -INFINITY);
    #pragma unroll 4
    for (int i = 0; i < 16; ++i) {
        float4 v = ((const float4*)(xb + (size_t)i * HW))[wq];
        s.x += v.x; s.y += v.y; s.z += v.z; s.w += v.w;
        m.x = fmaxf(m.x, v.x); m.y = fmaxf(m.y, v.y);
        m.z = fmaxf(m.z, v.z); m.w = fmaxf(m.w, v.w);
    }

    __shared__ float4 ls[16][32];
    __shared__ float4 lm[16][32];
    ls[cg][wq] = s;
    lm[cg][wq] = m;
    __syncthreads();

    if (t < 32) {
        float4 S = ls[0][t];
        float4 M = lm[0][t];
        #pragma unroll
        for (int g = 1; g < 16; ++g) {
            float4 a = ls[g][t];
            float4 c = lm[g][t];
            S.x += a.x; S.y += a.y; S.z += a.z; S.w += a.w;
            M.x = fmaxf(M.x, c.x); M.y = fmaxf(M.y, c.y);
            M.z = fmaxf(M.z, c.z); M.w = fmaxf(M.w, c.w);
        }
        const float inv = 1.0f / 256.0f;
        float4 o0 = make_float4(S.x * inv, M.x, S.y * inv, M.y);
        float4 o1 = make_float4(S.z * inv, M.z, S.w * inv, M.w);
        float4* yo = (float4*)(y2 + ((size_t)b * HW + (size_t)h * WW) * 2);
        yo[2 * t]     = o0;
        yo[2 * t + 1] = o1;
    }
}

// round-to-nearest-even f32 -> bf16 (low 16 bits)
__device__ __forceinline__ uint32_t f2bf(float f) {
    uint32_t u = __float_as_uint(f);
    return (u + 0x7FFFu + ((u >> 16) & 1u)) >> 16;
}
__device__ __forceinline__ float bf2f(uint32_t u) {
    return __uint_as_float(u << 16);
}

// ---------------------------------------------------------------------------
// Setup kernel: pack conv weights into MFMA B-fragment order, bf16.
// Bpre[kt][g][j][e], k = kt*32 + g*8 + e (K padded 98->128),
// j = GEMM channel: [0,49) dy (src ch 2j), [49,98) dx (src 2(j-49)+1),
// [98,147) mask (src j); padded to 160. Zero outside valid range.
// ---------------------------------------------------------------------------
__global__ __launch_bounds__(256) void prep_B(const float* __restrict__ w_off,
                                              uint16_t* __restrict__ Bpre) {
    const int idx = blockIdx.x * 256 + threadIdx.x;
    if (idx >= 4 * 4 * 160 * 8) return;
    const int e  = idx & 7;
    const int t1 = idx >> 3;
    const int j  = t1 % 160;
    const int t2 = t1 / 160;
    const int g  = t2 & 3;
    const int kt = t2 >> 2;
    const int k  = kt * 32 + g * 8 + e;
    uint16_t v = 0;
    if (k < 98 && j < 147) {
        const int ch = (j < 49) ? (2 * j) : ((j < 98) ? (2 * (j - 49) + 1) : j);
        v = (uint16_t)f2bf(w_off[(size_t)ch * 98 + k]);
    }
    Bpre[idx] = v;
}

// ---------------------------------------------------------------------------
// Kernel B: MFMA conv + deformable sampling + gate broadcast.
// Block = 256 threads (4 waves); wave wv owns positions [32wv, 32wv+32),
// 2 subs of 16. Conv per sub: im2col-A from patch LDS (8 x ds_read_u16 per
// fragment), pre-packed B fragments from Bpre (one 16B L2 load each),
// 1x10x4 tiles of mfma_f32_16x16x32_bf16. C round-trips via per-wave bf16
// LDS tile (MFMA layout -> tap-per-lane), then r8's sampling path.
// No min-waves hint (r3/r4/r6: hints cause GB-scale spill).
// ---------------------------------------------------------------------------
__global__ __launch_bounds__(256) void deform_att(
    const float* __restrict__ y2, const uint16_t* __restrict__ Bpre,
    const float* __restrict__ b_off,
    const float* __restrict__ w_dcn, const float* __restrict__ b_dcn,
    const float* __restrict__ bn_gamma, const float* __restrict__ bn_beta,
    const float* __restrict__ bn_mean, const float* __restrict__ bn_var,
    float* __restrict__ out)
{
    const int bh = blockIdx.x;
    const int b  = bh >> 7;
    const int h  = bh & 127;
    const int t  = threadIdx.x;
    const int wv = t >> 6;
    const int l  = t & 63;
    const bool act = (l < 49);
    const int ls = act ? l : 0;     // clamped tap index

    __shared__ uint32_t patch_pk[7][136];   // bf16x2 {mean,max}, zero-padded window
    __shared__ uint16_t cv[4][16][168];     // per-wave conv out, bf16, [pos][j]
    __shared__ float gate_row[128];

    const float2* y2b = (const float2*)y2 + (size_t)b * HW;

    // ---- stage the zero-padded bf16x2 patch window into LDS ----
    for (int i = t; i < 7 * 136; i += 256) {
        const int r  = i / 136;
        const int xi = i % 136;
        const int xx = xi - 3;
        const int yy = h + r - 3;
        uint32_t v = 0;
        if (yy >= 0 && yy < HH && xx >= 0 && xx < WW) {
            float2 g = y2b[yy * WW + xx];
            v = f2bf(g.x) | (f2bf(g.y) << 16);
        }
        patch_pk[r][xi] = v;
    }

    // per-lane (tap) sampling constants
    const float b_dy = b_off[2 * ls];
    const float b_dx = b_off[2 * ls + 1];
    const float b_m  = b_off[98 + ls];
    const float wd0 = w_dcn[ls];
    const float wd1 = w_dcn[49 + ls];
    const int kr = ls / 7;
    const int kc = ls % 7;
    const float bscale = bn_gamma[0] * rsqrtf(bn_var[0] + 1e-5f);
    const float gB = (b_dcn[0] - bn_mean[0]) * bscale + bn_beta[0];

    __syncthreads();

    const int m  = l & 15;          // M-row within tile (position offset)
    const int g  = l >> 4;          // k-group
    const uint16_t* patch_u16 = (const uint16_t*)patch_pk;
    uint16_t* cvw = &cv[wv][0][0];

    #pragma unroll 1
    for (int sub = 0; sub < 2; ++sub) {
        const int base = wv * 32 + sub * 16;
        const int pos  = base + m;

        // opaque B base per sub: defeats cross-sub LICM of 40 x 16B loads
        uintptr_t bpu = (uintptr_t)Bpre;
        asm volatile("" : "+s"(bpu));
        const uint16_t* bp = (const uint16_t*)bpu;

        f32x4 acc[10];
        #pragma unroll
        for (int nt = 0; nt < 10; ++nt) acc[nt] = (f32x4){0.f, 0.f, 0.f, 0.f};

        #pragma unroll
        for (int kt = 0; kt < 4; ++kt) {
            // ---- A fragment: 8 contiguous k from im2col(patch) ----
            union { uint16_t u[8]; bf16x8 v; } af;
            const int K0 = kt * 32 + g * 8;
            #pragma unroll
            for (int e = 0; e < 8; ++e) {
                const int k  = K0 + e;
                const int kk = (k < 98) ? k : 0;
                const int ci = (kk >= 49) ? 1 : 0;
                const int rc = kk - 49 * ci;
                const int r  = rc / 7;
                const int c  = rc - 7 * r;
                const uint16_t val = patch_u16[(r * 136 + pos + c) * 2 + ci];
                af.u[e] = (k < 98) ? val : (uint16_t)0;
            }
            // ---- B fragments (pre-packed, 16B each) + MFMA ----
            #pragma unroll
            for (int nt = 0; nt < 10; ++nt) {
                const int j = nt * 16 + m;
                const bf16x8 bfr = *(const bf16x8*)(bp + (((kt * 4 + g) * 160 + j) << 3));
                acc[nt] = __builtin_amdgcn_mfma_f32_16x16x32_bf16(af.v, bfr, acc[nt], 0, 0, 0);
            }
        }

        // ---- C -> cv (bf16): row=(g*4+q)=pos offset, col=j ----
        #pragma unroll
        for (int nt = 0; nt < 10; ++nt) {
            #pragma unroll
            for (int q = 0; q < 4; ++q) {
                cvw[(g * 4 + q) * 168 + nt * 16 + m] = (uint16_t)f2bf(acc[nt][q]);
            }
        }

        // ---- sampling: 16 positions, tap-per-lane (r8 path) ----
        #pragma unroll 8
        for (int pp = 0; pp < 16; ++pp) {
            const int posn = base + pp;

            const float dyv = bf2f(cvw[pp * 168 + ls])      + b_dy;
            const float dxv = bf2f(cvw[pp * 168 + 49 + ls]) + b_dx;
            const float mv  = bf2f(cvw[pp * 168 + 98 + ls]) + b_m;
            const float mk = 1.0f / (1.0f + __expf(-mv));

            const float fy = (float)(h + kr - 3) + dyv;
            const float fx = (float)(posn + kc - 3) + dxv;
            const float fly = floorf(fy), flx = floorf(fx);
            const int iy0 = (int)fly, ix0 = (int)flx;
            const int iy1 = iy0 + 1,  ix1 = ix0 + 1;
            const float wy1 = fy - fly, wy0 = 1.0f - wy1;
            const float wx1 = fx - flx, wx0 = 1.0f - wx1;

            const float vy0 = (iy0 >= 0 && iy0 < HH) ? 1.0f : 0.0f;
            const float vy1 = (iy1 >= 0 && iy1 < HH) ? 1.0f : 0.0f;
            const float vx0 = (ix0 >= 0 && ix0 < WW) ? 1.0f : 0.0f;
            const float vx1 = (ix1 >= 0 && ix1 < WW) ? 1.0f : 0.0f;

            const int cy0 = min(max(iy0, 0), HH - 1) * WW;
            const int cy1 = min(max(iy1, 0), HH - 1) * WW;
            const int cx0 = min(max(ix0, 0), WW - 1);
            const int cx1 = min(max(ix1, 0), WW - 1);

            const float w00 = wy0 * wx0 * vy0 * vx0;
            const float w01 = wy0 * wx1 * vy0 * vx1;
            const float w10 = wy1 * wx0 * vy1 * vx0;
            const float w11 = wy1 * wx1 * vy1 * vx1;

            const float2 g00 = y2b[cy0 + cx0];
            const float2 g01 = y2b[cy0 + cx1];
            const float2 g10 = y2b[cy1 + cx0];
            const float2 g11 = y2b[cy1 + cx1];

            const float v0s = g00.x * w00 + g01.x * w01 + g10.x * w10 + g11.x * w11;
            const float v1s = g00.y * w00 + g01.y * w01 + g10.y * w10 + g11.y * w11;

            float tval = mk * fmaf(v0s, wd0, v1s * wd1);
            tval = act ? tval : 0.0f;

            float ssum = tval;
            #pragma unroll
            for (int off = 1; off < 64; off <<= 1)
                ssum += __shfl_xor(ssum, off);

            if (l == 0) {
                const float o = ssum * bscale + gB;
                gate_row[posn] = 1.0f / (1.0f + __expf(-o));
            }
        }
    }

    __syncthreads();

    // ---- broadcast write: gate_row -> all 256 channels ----
    const size_t ob = (size_t)b * CC * HW + (size_t)h * WW;
    const float4* gr = (const float4*)gate_row;
    for (int idx = t; idx < CC * 32; idx += 256) {
        const int c  = idx >> 5;
        const int wq = idx & 31;
        ((float4*)(out + ob + (size_t)c * HW))[wq] = gr[wq];
    }
}

extern "C" void kernel_launch(void* const* d_in, const int* in_sizes, int n_in,
                              void* d_out, int out_size, void* d_ws, size_t ws_size,
                              hipStream_t stream) {
    const float* x        = (const float*)d_in[0];
    const float* w_off    = (const float*)d_in[1];
    const float* b_off    = (const float*)d_in[2];
    const float* w_dcn    = (const float*)d_in[3];
    const float* b_dcn    = (const float*)d_in[4];
    const float* bn_gamma = (const float*)d_in[5];
    const float* bn_beta  = (const float*)d_in[6];
    const float* bn_mean  = (const float*)d_in[7];
    const float* bn_var   = (const float*)d_in[8];
    float* out = (float*)d_out;

    float*    y2   = (float*)d_ws;                              // 1 MiB
    uint16_t* Bpre = (uint16_t*)((char*)d_ws + (1 << 20));      // 40 KiB

    reduce_meanmax<<<BB * HH, 512, 0, stream>>>(x, y2);
    prep_B<<<(4 * 4 * 160 * 8 + 255) / 256, 256, 0, stream>>>(w_off, Bpre);
    deform_att<<<BB * HH, 256, 0, stream>>>(y2, Bpre, b_off, w_dcn, b_dcn,
                                            bn_gamma, bn_beta, bn_mean, bn_var,
                                            out);
}

// Round 10
// 91.569 us; speedup vs baseline: 48.1869x; 1.0678x over previous
//
#include <hip/hip_runtime.h>
#include <cstdint>

#define BB 8
#define CC 256
#define HH 128
#define WW 128
#define HW (HH * WW)

typedef __attribute__((ext_vector_type(8))) short bf16x8;
typedef __attribute__((ext_vector_type(4))) float f32x4;

// ---------------------------------------------------------------------------
// Kernel A: per-position channel mean & max of x -> y2 (B, H*W, 2) float2
// interleaved {mean, max}. One block per (b, h) row; 512 threads.
// ---------------------------------------------------------------------------
__global__ __launch_bounds__(512) void reduce_meanmax(const float* __restrict__ x,
                                                      float* __restrict__ y2) {
    const int bh = blockIdx.x;
    const int b  = bh >> 7;
    const int h  = bh & 127;
    const int t  = threadIdx.x;
    const int wq = t & 31;       // float4 column: w = wq*4
    const int cg = t >> 5;       // channel group 0..15 (16 channels each)

    const float* xb = x + ((size_t)(b * CC + cg * 16) * HH + h) * WW;

    float4 s = make_float4(0.f, 0.f, 0.f, 0.f);
    float4 m = make_float4(-INFINITY, -INFINITY, -INFINITY, -INFINITY);
    #pragma unroll 4
    for (int i = 0; i < 16; ++i) {
        float4 v = ((const float4*)(xb + (size_t)i * HW))[wq];
        s.x += v.x; s.y += v.y; s.z += v.z; s.w += v.w;
        m.x = fmaxf(m.x, v.x); m.y = fmaxf(m.y, v.y);
        m.z = fmaxf(m.z, v.z); m.w = fmaxf(m.w, v.w);
    }

    __shared__ float4 ls[16][32];
    __shared__ float4 lm[16][32];
    ls[cg][wq] = s;
    lm[cg][wq] = m;
    __syncthreads();

    if (t < 32) {
        float4 S = ls[0][t];
        float4 M = lm[0][t];
        #pragma unroll
        for (int g = 1; g < 16; ++g) {
            float4 a = ls[g][t];
            float4 c = lm[g][t];
            S.x += a.x; S.y += a.y; S.z += a.z; S.w += a.w;
            M.x = fmaxf(M.x, c.x); M.y = fmaxf(M.y, c.y);
            M.z = fmaxf(M.z, c.z); M.w = fmaxf(M.w, c.w);
        }
        const float inv = 1.0f / 256.0f;
        float4 o0 = make_float4(S.x * inv, M.x, S.y * inv, M.y);
        float4 o1 = make_float4(S.z * inv, M.z, S.w * inv, M.w);
        float4* yo = (float4*)(y2 + ((size_t)b * HW + (size_t)h * WW) * 2);
        yo[2 * t]     = o0;
        yo[2 * t + 1] = o1;
    }
}

// round-to-nearest-even f32 -> bf16 (low 16 bits)
__device__ __forceinline__ uint32_t f2bf(float f) {
    uint32_t u = __float_as_uint(f);
    return (u + 0x7FFFu + ((u >> 16) & 1u)) >> 16;
}
__device__ __forceinline__ float bf2f(uint32_t u) {
    return __uint_as_float(u << 16);
}

// ---------------------------------------------------------------------------
// Setup kernel: pack conv weights into MFMA B-fragment order, bf16.
// Bpre[kt][g][j][e], k = kt*32 + g*8 + e (K padded 98->128),
// j: [0,49) dy, [49,98) dx, [98,147) mask; padded to 160.
// ---------------------------------------------------------------------------
__global__ __launch_bounds__(256) void prep_B(const float* __restrict__ w_off,
                                              uint16_t* __restrict__ Bpre) {
    const int idx = blockIdx.x * 256 + threadIdx.x;
    if (idx >= 4 * 4 * 160 * 8) return;
    const int e  = idx & 7;
    const int t1 = idx >> 3;
    const int j  = t1 % 160;
    const int t2 = t1 / 160;
    const int g  = t2 & 3;
    const int kt = t2 >> 2;
    const int k  = kt * 32 + g * 8 + e;
    uint16_t v = 0;
    if (k < 98 && j < 147) {
        const int ch = (j < 49) ? (2 * j) : ((j < 98) ? (2 * (j - 49) + 1) : j);
        v = (uint16_t)f2bf(w_off[(size_t)ch * 98 + k]);
    }
    Bpre[idx] = v;
}

// ---------------------------------------------------------------------------
// Kernel B: gate compute only (no output broadcast). Grid = 4096 blocks:
// one block per quarter-row (32 positions). 256 threads = 4 waves:
// wave (mhalf, nhalf) computes 16 positions x 5 N-tiles of the MFMA conv
// (acc = 20 VGPR, keeps total <=64 for the 32-waves/CU tier), shares conv
// output via block LDS cv, then each wave samples 8 positions tap-per-lane.
// Lessons kept: no min-waves hint (r3/r4/r6 spills); weights via pre-packed
// global fragments (L2); small per-wave state so nothing is hoist-worthy.
// ---------------------------------------------------------------------------
__global__ __launch_bounds__(256) void deform_gate(
    const float* __restrict__ y2, const uint16_t* __restrict__ Bpre,
    const float* __restrict__ b_off,
    const float* __restrict__ w_dcn, const float* __restrict__ b_dcn,
    const float* __restrict__ bn_gamma, const float* __restrict__ bn_beta,
    const float* __restrict__ bn_mean, const float* __restrict__ bn_var,
    float* __restrict__ gate)
{
    const int bid  = blockIdx.x;        // 4096
    const int rowg = bid >> 2;          // 0..1023 = b*128 + h
    const int qpos = (bid & 3) * 32;    // position base of this block
    const int b = rowg >> 7;
    const int h = rowg & 127;
    const int t = threadIdx.x;
    const int wv = t >> 6;
    const int l  = t & 63;
    const int mhalf = wv >> 1;          // which 16-position half
    const int nhalf = wv & 1;           // which 5 N-tiles
    const bool act = (l < 49);
    const int ls = act ? l : 0;

    __shared__ uint32_t patch_pk[7][40];   // bf16x2 {mean,max}, x in [qpos-3, qpos+34]
    __shared__ uint16_t cv[2][16][168];    // conv out bf16 [mhalf][pos][j]

    const float2* y2b = (const float2*)y2 + (size_t)b * HW;

    // ---- stage the zero-padded patch window ----
    for (int i = t; i < 7 * 40; i += 256) {
        const int r  = i / 40;
        const int xi = i % 40;
        const int xx = qpos + xi - 3;
        const int yy = h + r - 3;
        uint32_t v = 0;
        if (yy >= 0 && yy < HH && xx >= 0 && xx < WW) {
            float2 g2 = y2b[yy * WW + xx];
            v = f2bf(g2.x) | (f2bf(g2.y) << 16);
        }
        patch_pk[r][xi] = v;
    }

    // per-lane (tap) sampling constants
    const float b_dy = b_off[2 * ls];
    const float b_dx = b_off[2 * ls + 1];
    const float b_m  = b_off[98 + ls];
    const float wd0 = w_dcn[ls];
    const float wd1 = w_dcn[49 + ls];
    const int kr = ls / 7;
    const int kc = ls % 7;
    const float bscale = bn_gamma[0] * rsqrtf(bn_var[0] + 1e-5f);
    const float gB = (b_dcn[0] - bn_mean[0]) * bscale + bn_beta[0];

    __syncthreads();

    // ---- MFMA conv: 16 positions (mhalf) x 80 channels (nhalf) ----
    const int m = l & 15;               // position offset within half
    const int g = l >> 4;               // k-group
    const int plocal = mhalf * 16 + m;  // 0..31 position within block window
    const uint16_t* patch_u16 = (const uint16_t*)patch_pk;

    f32x4 acc[5];
    #pragma unroll
    for (int nn = 0; nn < 5; ++nn) acc[nn] = (f32x4){0.f, 0.f, 0.f, 0.f};

    #pragma unroll
    for (int kt = 0; kt < 4; ++kt) {
        union { uint16_t u[8]; bf16x8 v; } af;
        const int K0 = kt * 32 + g * 8;
        #pragma unroll
        for (int e = 0; e < 8; ++e) {
            const int k  = K0 + e;
            const int kk = (k < 98) ? k : 0;
            const int ci = (kk >= 49) ? 1 : 0;
            const int rc = kk - 49 * ci;
            const int r  = rc / 7;
            const int c  = rc - 7 * r;
            const uint16_t val = patch_u16[(r * 40 + plocal + c) * 2 + ci];
            af.u[e] = (k < 98) ? val : (uint16_t)0;
        }
        #pragma unroll
        for (int nn = 0; nn < 5; ++nn) {
            const int j = (nhalf * 5 + nn) * 16 + m;
            const bf16x8 bfr = *(const bf16x8*)(Bpre + (((kt * 4 + g) * 160 + j) << 3));
            acc[nn] = __builtin_amdgcn_mfma_f32_16x16x32_bf16(af.v, bfr, acc[nn], 0, 0, 0);
        }
    }

    // ---- C -> cv (bf16): row = g*4+q (pos offset), col = j ----
    #pragma unroll
    for (int nn = 0; nn < 5; ++nn) {
        #pragma unroll
        for (int q = 0; q < 4; ++q) {
            cv[mhalf][g * 4 + q][(nhalf * 5 + nn) * 16 + m] = (uint16_t)f2bf(acc[nn][q]);
        }
    }
    __syncthreads();

    // ---- sampling: wave wv owns positions [8*wv, 8*wv+8) of the 32 ----
    const uint16_t* cvp = &cv[0][0][0];
    #pragma unroll 4
    for (int pi = 0; pi < 8; ++pi) {
        const int pp = wv * 8 + pi;          // 0..31 (wave-uniform)
        const int posn = qpos + pp;          // global x position
        const int cbase = pp * 168;          // cv[2][16][168] flat: (mh*16+pr)*168

        const float dyv = bf2f(cvp[cbase + ls])      + b_dy;
        const float dxv = bf2f(cvp[cbase + 49 + ls]) + b_dx;
        const float mv  = bf2f(cvp[cbase + 98 + ls]) + b_m;
        const float mk = 1.0f / (1.0f + __expf(-mv));

        const float fy = (float)(h + kr - 3) + dyv;
        const float fx = (float)(posn + kc - 3) + dxv;
        const float fly = floorf(fy), flx = floorf(fx);
        const int iy0 = (int)fly, ix0 = (int)flx;
        const int iy1 = iy0 + 1,  ix1 = ix0 + 1;
        const float wy1 = fy - fly, wy0 = 1.0f - wy1;
        const float wx1 = fx - flx, wx0 = 1.0f - wx1;

        const float vy0 = (iy0 >= 0 && iy0 < HH) ? 1.0f : 0.0f;
        const float vy1 = (iy1 >= 0 && iy1 < HH) ? 1.0f : 0.0f;
        const float vx0 = (ix0 >= 0 && ix0 < WW) ? 1.0f : 0.0f;
        const float vx1 = (ix1 >= 0 && ix1 < WW) ? 1.0f : 0.0f;

        const int cy0 = min(max(iy0, 0), HH - 1) * WW;
        const int cy1 = min(max(iy1, 0), HH - 1) * WW;
        const int cx0 = min(max(ix0, 0), WW - 1);
        const int cx1 = min(max(ix1, 0), WW - 1);

        const float w00 = wy0 * wx0 * vy0 * vx0;
        const float w01 = wy0 * wx1 * vy0 * vx1;
        const float w10 = wy1 * wx0 * vy1 * vx0;
        const float w11 = wy1 * wx1 * vy1 * vx1;

        const float2 g00 = y2b[cy0 + cx0];
        const float2 g01 = y2b[cy0 + cx1];
        const float2 g10 = y2b[cy1 + cx0];
        const float2 g11 = y2b[cy1 + cx1];

        const float v0s = g00.x * w00 + g01.x * w01 + g10.x * w10 + g11.x * w11;
        const float v1s = g00.y * w00 + g01.y * w01 + g10.y * w10 + g11.y * w11;

        float tval = mk * fmaf(v0s, wd0, v1s * wd1);
        tval = act ? tval : 0.0f;

        float ssum = tval;
        #pragma unroll
        for (int off = 1; off < 64; off <<= 1)
            ssum += __shfl_xor(ssum, off);

        if (l == 0) {
            const float o = ssum * bscale + gB;
            gate[(size_t)rowg * WW + posn] = 1.0f / (1.0f + __expf(-o));
        }
    }
}

// ---------------------------------------------------------------------------
// Kernel C: broadcast gate (B,H,W) to out (B,C,H,W). Pure write-bound:
// gate is 512 KB (L2-resident), out is 134 MB at HBM write BW.
// ---------------------------------------------------------------------------
__global__ __launch_bounds__(256) void bcast_gate(const float* __restrict__ gate,
                                                  float* __restrict__ out) {
    const int tid = blockIdx.x * 256 + threadIdx.x;   // 524288 threads
    const float4* g4 = (const float4*)gate;
    float4* o4 = (float4*)out;
    #pragma unroll
    for (int rep = 0; rep < 16; ++rep) {
        const int f   = tid + rep * (1 << 19);  // out float4 index
        const int hw4 = f & 4095;               // HW/4
        const int bc  = f >> 12;                // b*256 + c
        const int bb  = bc >> 8;                // b
        o4[f] = g4[bb * 4096 + hw4];
    }
}

extern "C" void kernel_launch(void* const* d_in, const int* in_sizes, int n_in,
                              void* d_out, int out_size, void* d_ws, size_t ws_size,
                              hipStream_t stream) {
    const float* x        = (const float*)d_in[0];
    const float* w_off    = (const float*)d_in[1];
    const float* b_off    = (const float*)d_in[2];
    const float* w_dcn    = (const float*)d_in[3];
    const float* b_dcn    = (const float*)d_in[4];
    const float* bn_gamma = (const float*)d_in[5];
    const float* bn_beta  = (const float*)d_in[6];
    const float* bn_mean  = (const float*)d_in[7];
    const float* bn_var   = (const float*)d_in[8];
    float* out = (float*)d_out;

    float*    y2   = (float*)d_ws;                                   // 1 MiB
    uint16_t* Bpre = (uint16_t*)((char*)d_ws + (1 << 20));           // 40 KiB
    float*    gate = (float*)((char*)d_ws + (1 << 20) + (1 << 16));  // 512 KiB

    reduce_meanmax<<<BB * HH, 512, 0, stream>>>(x, y2);
    prep_B<<<(4 * 4 * 160 * 8 + 255) / 256, 256, 0, stream>>>(w_off, Bpre);
    deform_gate<<<4 * BB * HH, 256, 0, stream>>>(y2, Bpre, b_off, w_dcn, b_dcn,
                                                 bn_gamma, bn_beta, bn_mean, bn_var,
                                                 gate);
    bcast_gate<<<2048, 256, 0, stream>>>(gate, out);
}

// Round 12
// 74.574 us; speedup vs baseline: 59.1680x; 1.2279x over previous
//
#include <hip/hip_runtime.h>
#include <cstdint>

#define BB 8
#define CC 256
#define HH 128
#define WW 128
#define HW (HH * WW)

typedef __attribute__((ext_vector_type(8))) short bf16x8;
typedef __attribute__((ext_vector_type(4))) float f32x4;

// ---------------------------------------------------------------------------
// Kernel A: per-position channel mean & max of x -> y2 (B, H*W, 2) float2
// interleaved {mean, max}. One block per (b, h) row; 512 threads.
// ---------------------------------------------------------------------------
__global__ __launch_bounds__(512) void reduce_meanmax(const float* __restrict__ x,
                                                      float* __restrict__ y2) {
    const int bh = blockIdx.x;
    const int b  = bh >> 7;
    const int h  = bh & 127;
    const int t  = threadIdx.x;
    const int wq = t & 31;       // float4 column: w = wq*4
    const int cg = t >> 5;       // channel group 0..15 (16 channels each)

    const float* xb = x + ((size_t)(b * CC + cg * 16) * HH + h) * WW;

    float4 s = make_float4(0.f, 0.f, 0.f, 0.f);
    float4 m = make_float4(-INFINITY, -INFINITY, -INFINITY, -INFINITY);
    #pragma unroll 4
    for (int i = 0; i < 16; ++i) {
        float4 v = ((const float4*)(xb + (size_t)i * HW))[wq];
        s.x += v.x; s.y += v.y; s.z += v.z; s.w += v.w;
        m.x = fmaxf(m.x, v.x); m.y = fmaxf(m.y, v.y);
        m.z = fmaxf(m.z, v.z); m.w = fmaxf(m.w, v.w);
    }

    __shared__ float4 ls[16][32];
    __shared__ float4 lm[16][32];
    ls[cg][wq] = s;
    lm[cg][wq] = m;
    __syncthreads();

    if (t < 32) {
        float4 S = ls[0][t];
        float4 M = lm[0][t];
        #pragma unroll
        for (int g = 1; g < 16; ++g) {
            float4 a = ls[g][t];
            float4 c = lm[g][t];
            S.x += a.x; S.y += a.y; S.z += a.z; S.w += a.w;
            M.x = fmaxf(M.x, c.x); M.y = fmaxf(M.y, c.y);
            M.z = fmaxf(M.z, c.z); M.w = fmaxf(M.w, c.w);
        }
        const float inv = 1.0f / 256.0f;
        float4 o0 = make_float4(S.x * inv, M.x, S.y * inv, M.y);
        float4 o1 = make_float4(S.z * inv, M.z, S.w * inv, M.w);
        float4* yo = (float4*)(y2 + ((size_t)b * HW + (size_t)h * WW) * 2);
        yo[2 * t]     = o0;
        yo[2 * t + 1] = o1;
    }
}

// round-to-nearest-even f32 -> bf16 (low 16 bits)
__device__ __forceinline__ uint32_t f2bf(float f) {
    uint32_t u = __float_as_uint(f);
    return (u + 0x7FFFu + ((u >> 16) & 1u)) >> 16;
}
__device__ __forceinline__ float bf2f(uint32_t u) {
    return __uint_as_float(u << 16);
}

// ---------------------------------------------------------------------------
// Setup kernel: pack conv weights into MFMA B-fragment order, bf16.
// Bpre[kt][g][j][e], k = kt*32 + g*8 + e (K padded 98->128),
// j: [0,49) dy, [49,98) dx, [98,147) mask; padded to 160.
// ---------------------------------------------------------------------------
__global__ __launch_bounds__(256) void prep_B(const float* __restrict__ w_off,
                                              uint16_t* __restrict__ Bpre) {
    const int idx = blockIdx.x * 256 + threadIdx.x;
    if (idx >= 4 * 4 * 160 * 8) return;
    const int e  = idx & 7;
    const int t1 = idx >> 3;
    const int j  = t1 % 160;
    const int t2 = t1 / 160;
    const int g  = t2 & 3;
    const int kt = t2 >> 2;
    const int k  = kt * 32 + g * 8 + e;
    uint16_t v = 0;
    if (k < 98 && j < 147) {
        const int ch = (j < 49) ? (2 * j) : ((j < 98) ? (2 * (j - 49) + 1) : j);
        v = (uint16_t)f2bf(w_off[(size_t)ch * 98 + k]);
    }
    Bpre[idx] = v;
}

// ---------------------------------------------------------------------------
// Kernel B: gate compute + fused broadcast write. Grid = 4096 blocks (one per
// quarter-row = 32 positions), 256 threads = 4 waves.
// Phase 1: wave (mhalf, nhalf) computes 16 pos x 5 N-tiles of the MFMA conv;
// conv out shared via block LDS cv. Phase 2: each wave samples 8 positions
// tap-per-lane -> gate_blk[32] in LDS. Phase 3: block writes its own
// out[b, :, h, qpos:qpos+32] slab (32 KB, nontemporal) -- per-block writes
// overlap other blocks' compute (r10 lesson: a separate bcast kernel is a
// serial +20 us stage).
// Lessons kept: no min-waves hint (r3/r4/r6 spills); pre-packed B fragments.
// ---------------------------------------------------------------------------
__global__ __launch_bounds__(256) void deform_gate(
    const float* __restrict__ y2, const uint16_t* __restrict__ Bpre,
    const float* __restrict__ b_off,
    const float* __restrict__ w_dcn, const float* __restrict__ b_dcn,
    const float* __restrict__ bn_gamma, const float* __restrict__ bn_beta,
    const float* __restrict__ bn_mean, const float* __restrict__ bn_var,
    float* __restrict__ out)
{
    const int bid  = blockIdx.x;        // 4096
    const int rowg = bid >> 2;          // 0..1023 = b*128 + h
    const int qpos = (bid & 3) * 32;    // position base of this block
    const int b = rowg >> 7;
    const int h = rowg & 127;
    const int t = threadIdx.x;
    const int wv = t >> 6;
    const int l  = t & 63;
    const int mhalf = wv >> 1;          // which 16-position half
    const int nhalf = wv & 1;           // which 5 N-tiles
    const bool act = (l < 49);
    const int ls = act ? l : 0;

    __shared__ uint32_t patch_pk[7][40];   // bf16x2 {mean,max}, x in [qpos-3, qpos+34]
    __shared__ uint16_t cv[2][16][168];    // conv out bf16 [mhalf][pos][j]
    __shared__ float gate_blk[32];

    const float2* y2b = (const float2*)y2 + (size_t)b * HW;

    // ---- stage the zero-padded patch window ----
    for (int i = t; i < 7 * 40; i += 256) {
        const int r  = i / 40;
        const int xi = i % 40;
        const int xx = qpos + xi - 3;
        const int yy = h + r - 3;
        uint32_t v = 0;
        if (yy >= 0 && yy < HH && xx >= 0 && xx < WW) {
            float2 g2 = y2b[yy * WW + xx];
            v = f2bf(g2.x) | (f2bf(g2.y) << 16);
        }
        patch_pk[r][xi] = v;
    }

    // per-lane (tap) sampling constants
    const float b_dy = b_off[2 * ls];
    const float b_dx = b_off[2 * ls + 1];
    const float b_m  = b_off[98 + ls];
    const float wd0 = w_dcn[ls];
    const float wd1 = w_dcn[49 + ls];
    const int kr = ls / 7;
    const int kc = ls % 7;
    const float bscale = bn_gamma[0] * rsqrtf(bn_var[0] + 1e-5f);
    const float gB = (b_dcn[0] - bn_mean[0]) * bscale + bn_beta[0];

    __syncthreads();

    // ---- MFMA conv: 16 positions (mhalf) x 80 channels (nhalf) ----
    const int m = l & 15;               // position offset within half
    const int g = l >> 4;               // k-group
    const int plocal = mhalf * 16 + m;  // 0..31 position within block window
    const uint16_t* patch_u16 = (const uint16_t*)patch_pk;

    f32x4 acc[5];
    #pragma unroll
    for (int nn = 0; nn < 5; ++nn) acc[nn] = (f32x4){0.f, 0.f, 0.f, 0.f};

    #pragma unroll
    for (int kt = 0; kt < 4; ++kt) {
        union { uint16_t u[8]; bf16x8 v; } af;
        const int K0 = kt * 32 + g * 8;
        #pragma unroll
        for (int e = 0; e < 8; ++e) {
            const int k  = K0 + e;
            const int kk = (k < 98) ? k : 0;
            const int ci = (kk >= 49) ? 1 : 0;
            const int rc = kk - 49 * ci;
            const int r  = rc / 7;
            const int c  = rc - 7 * r;
            const uint16_t val = patch_u16[(r * 40 + plocal + c) * 2 + ci];
            af.u[e] = (k < 98) ? val : (uint16_t)0;
        }
        #pragma unroll
        for (int nn = 0; nn < 5; ++nn) {
            const int j = (nhalf * 5 + nn) * 16 + m;
            const bf16x8 bfr = *(const bf16x8*)(Bpre + (((kt * 4 + g) * 160 + j) << 3));
            acc[nn] = __builtin_amdgcn_mfma_f32_16x16x32_bf16(af.v, bfr, acc[nn], 0, 0, 0);
        }
    }

    // ---- C -> cv (bf16): row = g*4+q (pos offset), col = j ----
    #pragma unroll
    for (int nn = 0; nn < 5; ++nn) {
        #pragma unroll
        for (int q = 0; q < 4; ++q) {
            cv[mhalf][g * 4 + q][(nhalf * 5 + nn) * 16 + m] = (uint16_t)f2bf(acc[nn][q]);
        }
    }
    __syncthreads();

    // ---- sampling: wave wv owns positions [8*wv, 8*wv+8) of the 32 ----
    const uint16_t* cvp = &cv[0][0][0];
    #pragma unroll 4
    for (int pi = 0; pi < 8; ++pi) {
        const int pp = wv * 8 + pi;          // 0..31 (wave-uniform)
        const int posn = qpos + pp;          // global x position
        const int cbase = pp * 168;          // cv[2][16][168] flat: (mh*16+pr)*168

        const float dyv = bf2f(cvp[cbase + ls])      + b_dy;
        const float dxv = bf2f(cvp[cbase + 49 + ls]) + b_dx;
        const float mv  = bf2f(cvp[cbase + 98 + ls]) + b_m;
        const float mk = 1.0f / (1.0f + __expf(-mv));

        const float fy = (float)(h + kr - 3) + dyv;
        const float fx = (float)(posn + kc - 3) + dxv;
        const float fly = floorf(fy), flx = floorf(fx);
        const int iy0 = (int)fly, ix0 = (int)flx;
        const int iy1 = iy0 + 1,  ix1 = ix0 + 1;
        const float wy1 = fy - fly, wy0 = 1.0f - wy1;
        const float wx1 = fx - flx, wx0 = 1.0f - wx1;

        const float vy0 = (iy0 >= 0 && iy0 < HH) ? 1.0f : 0.0f;
        const float vy1 = (iy1 >= 0 && iy1 < HH) ? 1.0f : 0.0f;
        const float vx0 = (ix0 >= 0 && ix0 < WW) ? 1.0f : 0.0f;
        const float vx1 = (ix1 >= 0 && ix1 < WW) ? 1.0f : 0.0f;

        const int cy0 = min(max(iy0, 0), HH - 1) * WW;
        const int cy1 = min(max(iy1, 0), HH - 1) * WW;
        const int cx0 = min(max(ix0, 0), WW - 1);
        const int cx1 = min(max(ix1, 0), WW - 1);

        const float w00 = wy0 * wx0 * vy0 * vx0;
        const float w01 = wy0 * wx1 * vy0 * vx1;
        const float w10 = wy1 * wx0 * vy1 * vx0;
        const float w11 = wy1 * wx1 * vy1 * vx1;

        const float2 g00 = y2b[cy0 + cx0];
        const float2 g01 = y2b[cy0 + cx1];
        const float2 g10 = y2b[cy1 + cx0];
        const float2 g11 = y2b[cy1 + cx1];

        const float v0s = g00.x * w00 + g01.x * w01 + g10.x * w10 + g11.x * w11;
        const float v1s = g00.y * w00 + g01.y * w01 + g10.y * w10 + g11.y * w11;

        float tval = mk * fmaf(v0s, wd0, v1s * wd1);
        tval = act ? tval : 0.0f;

        float ssum = tval;
        #pragma unroll
        for (int off = 1; off < 64; off <<= 1)
            ssum += __shfl_xor(ssum, off);

        if (l == 0) {
            const float o = ssum * bscale + gB;
            gate_blk[pp] = 1.0f / (1.0f + __expf(-o));
        }
    }

    __syncthreads();

    // ---- fused broadcast write: out[b, :, h, qpos:qpos+32] (32 KB/block) ----
    // idx -> (c = idx>>3, q4 = idx&7): 8 lanes cover one channel's 32 floats
    // (128 B contiguous); LDS f32x4 reads are 8-way same-address broadcasts.
    const size_t ob = (size_t)b * CC * HW + (size_t)h * WW + qpos;
    const f32x4* gb4 = (const f32x4*)gate_blk;
    #pragma unroll
    for (int it = 0; it < 8; ++it) {
        const int idx = it * 256 + t;
        const int c   = idx >> 3;
        const int q4  = idx & 7;
        __builtin_nontemporal_store(gb4[q4], (f32x4*)(out + ob + (size_t)c * HW) + q4);
    }
}

extern "C" void kernel_launch(void* const* d_in, const int* in_sizes, int n_in,
                              void* d_out, int out_size, void* d_ws, size_t ws_size,
                              hipStream_t stream) {
    const float* x        = (const float*)d_in[0];
    const float* w_off    = (const float*)d_in[1];
    const float* b_off    = (const float*)d_in[2];
    const float* w_dcn    = (const float*)d_in[3];
    const float* b_dcn    = (const float*)d_in[4];
    const float* bn_gamma = (const float*)d_in[5];
    const float* bn_beta  = (const float*)d_in[6];
    const float* bn_mean  = (const float*)d_in[7];
    const float* bn_var   = (const float*)d_in[8];
    float* out = (float*)d_out;

    float*    y2   = (float*)d_ws;                              // 1 MiB
    uint16_t* Bpre = (uint16_t*)((char*)d_ws + (1 << 20));      // 40 KiB

    prep_B<<<(4 * 4 * 160 * 8 + 255) / 256, 256, 0, stream>>>(w_off, Bpre);
    reduce_meanmax<<<BB * HH, 512, 0, stream>>>(x, y2);
    deform_gate<<<4 * BB * HH, 256, 0, stream>>>(y2, Bpre, b_off, w_dcn, b_dcn,
                                                 bn_gamma, bn_beta, bn_mean, bn_var,
                                                 out);
}